// Round 9
// baseline (19.845 us; speedup 1.0000x reference)
//
#include <hip/hip_runtime.h>
#include <hip/hip_bf16.h>

// HeteroSoap via MFMA: c[s*4+n][ab] = sum_atoms f_sn * Y_ab = 16x16 GEMM, K=N.
// Round 9 = round-7's dword-packed data path (proven correct) x round-6's
// nb=1024 config (proven fastest): wave-private LDS tile [comp][atom] of
// dwords, lo16 = f (species one-hot), hi16 = Y. 16 ds_write_b32 +
// 4 ds_read_b128 per 64-atom chunk (halves round-6's LDS-pipe load; the
// 4 reads feed BOTH A and B fragments). XOR swizzle (idx ^ (c&7)<<2) same
// on write and read. Same atom<->k map for A and B -> MFMA k-order cancels.
// Tail fused: reduce+finalize in one kernel via last-block-done (accum
// block 0 zeroes c+counter each launch; kernel boundary orders it).

typedef short short8 __attribute__((ext_vector_type(8)));
typedef float f32x4 __attribute__((ext_vector_type(4)));
typedef unsigned int uint4v __attribute__((ext_vector_type(4)));

#define NB 1024

__device__ __forceinline__ unsigned short bfu(float x) {
    __hip_bfloat16 h = __float2bfloat16(x);
    unsigned short s; __builtin_memcpy(&s, &h, 2); return s;
}

__global__ void __launch_bounds__(256) soap_accum(
    const float* __restrict__ coo, const int* __restrict__ numbers,
    int N, float* __restrict__ partials, float* __restrict__ c_ws,
    int* __restrict__ counter)
{
    __shared__ unsigned int lT[4][16][64];  // [wave][comp][atom] f|Y<<16, 16 KB

    // Per-launch init of the fused-tail state. Runs before this kernel ends;
    // the reduce kernel starts only after ALL accum blocks complete.
    if (blockIdx.x == 0) {
        if (threadIdx.x < 256) c_ws[threadIdx.x] = 0.f;
        if (threadIdx.x == 0) *counter = 0;
    }

    const int lane = threadIdx.x & 63;
    const int w = threadIdx.x >> 6;
    const int g = lane >> 4;            // k-group
    const int comp = lane & 15;         // fragment index dim (A row / B col)

    unsigned int* lTw = &lT[w][0][0];

    // Loop-invariant read pointers (round-7 proven): element e of group at
    // base (X)^t4 holds atom X+e; same map for A (lo16) and B (hi16).
    const unsigned t4 = (unsigned)((comp & 7) << 2);
    const unsigned rb = (unsigned)(comp << 6);
    const uint4v* q0p = (const uint4v*)&lTw[rb + (( 8u * g)          ^ t4)];
    const uint4v* q1p = (const uint4v*)&lTw[rb + (( 8u * g + 4)      ^ t4)];
    const uint4v* q2p = (const uint4v*)&lTw[rb + ((32u + 8u * g)     ^ t4)];
    const uint4v* q3p = (const uint4v*)&lTw[rb + ((32u + 8u * g + 4) ^ t4)];

    f32x4 acc = {0.f, 0.f, 0.f, 0.f};

    const int stride = NB * 256;        // 4 waves x 64 atoms per block per iter
    for (int base = (blockIdx.x * 4 + w) * 64; base < N; base += stride) {
        int i = base + lane;
        int ic = i < N ? i : N - 1;
        float x = coo[3 * ic + 0] * 0.5f;   // xyz = coo / UNIT, UNIT = 2
        float y = coo[3 * ic + 1] * 0.5f;
        float z = coo[3 * ic + 2] * 0.5f;
        int num = numbers[ic];

        float r2 = x * x + y * y + z * z;
        float dq = sqrtf(r2);
        float tc = fmaxf(1.f - dq * (1.f / 3.f), 0.f);  // == branch version bit-exact
        float r = __expf(-0.5f * r2) * (tc * tc);
        if (i >= N) r = 0.f;                 // tail: zero f-row kills the atom

        float f0 = r, f1 = r * r2, f2 = f1 * r2, f3 = f2 * r2;

        // Solid harmonics, packed (L+1)x(L+1) row-major:
        const float Y00 = 0.28209479177387814f;
        float re11 = -0.34549414947133550f * x;
        float im11 = -0.34549414947133550f * y;
        float re10 =  0.48860251190291992f * z;
        float re22 = -1.11803398874989490f * (x * re11 - y * im11);
        float im22 = -1.11803398874989490f * (x * im11 + y * re11);
        float re21 =  2.23606797749978970f * z * re11;
        float im21 =  2.23606797749978970f * z * im11;
        float re20 =  1.93649167310370850f * (z * re10 - 0.16286750396763996f * r2);
        float re33 = -1.08012344973464350f * (x * re22 - y * im22);
        float im33 = -1.08012344973464350f * (x * im22 + y * re22);
        float re32 =  2.64575131106459070f * z * re22;
        float im32 =  2.64575131106459070f * z * im22;
        float re31 =  2.09165006633518890f * (z * re21 - 0.44721359549995793f * r2 * re11);
        float im31 =  2.09165006633518890f * (z * im21 - 0.44721359549995793f * r2 * im11);
        float re30 =  1.97202659436653870f * (z * re20 - 0.51639777949432220f * r2 * re10);

        unsigned short yb[16];
        yb[0] = bfu(Y00);  yb[1] = bfu(im11); yb[2]  = bfu(im22); yb[3]  = bfu(im33);
        yb[4] = bfu(re11); yb[5] = bfu(re10); yb[6]  = bfu(im21); yb[7]  = bfu(im32);
        yb[8] = bfu(re22); yb[9] = bfu(re21); yb[10] = bfu(re20); yb[11] = bfu(im31);
        yb[12] = bfu(re33); yb[13] = bfu(re32); yb[14] = bfu(re31); yb[15] = bfu(re30);

        unsigned short hb[4] = {bfu(f0), bfu(f1), bfu(f2), bfu(f3)};

        // Packed swizzled stores: lane owns atom-column `lane`, 16 dwords.
#pragma unroll
        for (int c = 0; c < 16; ++c) {
            unsigned v = ((unsigned)yb[c] << 16)
                       | (unsigned)((num == (c >> 2)) ? hb[c & 3] : (unsigned short)0);
            lTw[(c << 6) + (lane ^ ((c & 7) << 2))] = v;
        }

        // Wave-private tile: compiler orders the aliasing writes/reads.
        uint4v q0 = *q0p, q1 = *q1p, q2 = *q2p, q3 = *q3p;

        short8 A0, B0, A1, B1;
#pragma unroll
        for (int e = 0; e < 4; ++e) {
            A0[e]     = (short)(q0[e] & 0xffffu);
            A0[4 + e] = (short)(q1[e] & 0xffffu);
            B0[e]     = (short)(q0[e] >> 16);
            B0[4 + e] = (short)(q1[e] >> 16);
            A1[e]     = (short)(q2[e] & 0xffffu);
            A1[4 + e] = (short)(q3[e] & 0xffffu);
            B1[e]     = (short)(q2[e] >> 16);
            B1[4 + e] = (short)(q3[e] >> 16);
        }

        acc = __builtin_amdgcn_mfma_f32_16x16x32_bf16(A0, B0, acc, 0, 0, 0);
        acc = __builtin_amdgcn_mfma_f32_16x16x32_bf16(A1, B1, acc, 0, 0, 0);
    }

    // C/D layout (m89): lane, reg rr -> c[i=(lane>>4)*4+rr][j=lane&15].
    // Reuse this wave's (idle, wave-private) tile as the reduce buffer.
    float* credw = (float*)&lT[w][0][0];
#pragma unroll
    for (int rr = 0; rr < 4; ++rr)
        credw[((lane >> 4) * 4 + rr) * 16 + (lane & 15)] = acc[rr];
    __syncthreads();

    int tt = threadIdx.x;
    partials[blockIdx.x * 256 + tt] =
        ((float*)&lT[0][0][0])[tt] + ((float*)&lT[1][0][0])[tt] +
        ((float*)&lT[2][0][0])[tt] + ((float*)&lT[3][0][0])[tt];
}

// Fused reduce + finalize, 32 blocks. Each block sums its slice of partials
// and atomically adds into c_ws; the last block to finish performs the
// Yr/Yi/nnl contraction and writes the 1024 outputs.
__global__ void __launch_bounds__(256) soap_reduce_final(
    const float* __restrict__ partials, float* __restrict__ c_ws,
    int* __restrict__ counter, float* __restrict__ out)
{
    __shared__ float cs[256];
    __shared__ int lastflag;
    int t = threadIdx.x;

    float v = 0.f;
    for (int r = blockIdx.x; r < NB; r += 32)
        v += partials[r * 256 + t];           // coalesced
    atomicAdd(&c_ws[t], v);                   // 32 adds/address, device scope
    __syncthreads();                          // all 256 adds of this block done
    if (t == 0) {
        __threadfence();                      // release our adds
        lastflag = (atomicAdd(counter, 1) == 31);
    }
    __syncthreads();
    if (!lastflag) return;

    __threadfence();                          // acquire other blocks' adds
    cs[t] = __hip_atomic_load(&c_ws[t], __ATOMIC_RELAXED,
                              __HIP_MEMORY_SCOPE_AGENT);  // L1-bypassing load
    __syncthreads();

    // p1[a,b,n,m,l] = sum_{j<=l} w_j c[b,m,l,j] c[a,n,l,j] (w=1 if j==l else 2)
    // p2[a,b,n,m,l] = sum_{i<l}  2  c[b,m,i,l] c[a,n,i,l]
    // out = (p1+p2) * nnl[n,m,l]
    const float fact[7] = {1.f, 1.f, 2.f, 6.f, 24.f, 120.f, 720.f};
#pragma unroll
    for (int k = 0; k < 4; ++k) {
        int o = k * 256 + t;
        int l = o & 3, m = (o >> 2) & 3, n = (o >> 4) & 3,
            b = (o >> 6) & 3, a = (o >> 8) & 3;
        const float* cbm = &cs[(b * 4 + m) * 16];
        const float* can = &cs[(a * 4 + n) * 16];
        float vv = 0.f;
        for (int j = 0; j <= l; ++j) {
            float wgt = (j == l) ? 1.f : 2.f;
            vv += wgt * cbm[l * 4 + j] * can[l * 4 + j];
        }
        for (int i = 0; i < l; ++i)
            vv += 2.f * cbm[i * 4 + l] * can[i * 4 + l];
        float an = 1.0f / ((float)(2 * l + 1) * (float)(1 << (2 * n + l)) * fact[n] * fact[n + l]);
        float am = 1.0f / ((float)(2 * l + 1) * (float)(1 << (2 * m + l)) * fact[m] * fact[m + l]);
        out[o] = vv * sqrtf(an * am);
    }
}

extern "C" void kernel_launch(void* const* d_in, const int* in_sizes, int n_in,
                              void* d_out, int out_size, void* d_ws, size_t ws_size,
                              hipStream_t stream)
{
    const float* coo = (const float*)d_in[0];
    const int* numbers = (const int*)d_in[1];
    int N = in_sizes[1];                 // 1,000,000 atoms

    float* c_ws = (float*)d_ws;          // [256] accumulated c
    int* counter = (int*)((float*)d_ws + 256);  // ticket counter
    float* partials = (float*)d_ws + 512;       // [NB*256] stage-1 partials
    // ws requirement: (512 + 262144) * 4 B ~= 1.05 MB.

    hipLaunchKernelGGL(soap_accum, dim3(NB), dim3(256), 0, stream,
                       coo, numbers, N, partials, c_ws, counter);
    hipLaunchKernelGGL(soap_reduce_final, dim3(32), dim3(256), 0, stream,
                       partials, c_ws, counter, (float*)d_out);
}

// Round 10
// 18.245 us; speedup vs baseline: 1.0877x; 1.0877x over previous
//
#include <hip/hip_runtime.h>
#include <hip/hip_bf16.h>

// HeteroSoap via MFMA: c[s*4+n][ab] = sum_atoms f_sn * Y_ab = 16x16 GEMM, K=N.
// Round 10 = round-9 structure with three op-count cuts (evidence r2..r9:
// wall time tracks issued-instruction count, not pipelining/occupancy):
//  1) LDS pack via v_cvt_pk_bf16_f32 (1 instr makes the dword: lo=f, hi=Y)
//     replacing per-scalar bfloat conversions + shift/or (~35 VALU/iter).
//  2) NB=512: 8 chunks/wave (trend: fewer blocks + more iters/wave wins).
//  3) Tail reduce halves (512 partial rows).
// Data path unchanged & proven: wave-private dword tile [comp][atom]
// (lo16=f one-hot, hi16=Y), XOR swizzle (idx ^ (c&7)<<2) same on write and
// read, 16 ds_write_b32 + 4 ds_read_b128 per 64-atom chunk, same atom<->k
// map for A and B so MFMA k-order cancels; C/D layout per m89.
// Tail: fused reduce+finalize via last-block-done (c_ws/counter zeroed by
// accum block 0; kernel boundary orders it).

typedef short short8 __attribute__((ext_vector_type(8)));
typedef float f32x4 __attribute__((ext_vector_type(4)));
typedef unsigned int uint4v __attribute__((ext_vector_type(4)));

#define NB 512

__global__ void __launch_bounds__(256) soap_accum(
    const float* __restrict__ coo, const int* __restrict__ numbers,
    int N, float* __restrict__ partials, float* __restrict__ c_ws,
    int* __restrict__ counter)
{
    __shared__ unsigned int lT[4][16][64];  // [wave][comp][atom] f|Y<<16, 16 KB

    // Per-launch init of fused-tail state (accum ends before reduce starts).
    if (blockIdx.x == 0) {
        if (threadIdx.x < 256) c_ws[threadIdx.x] = 0.f;
        if (threadIdx.x == 0) *counter = 0;
    }

    const int lane = threadIdx.x & 63;
    const int w = threadIdx.x >> 6;
    const int g = lane >> 4;            // k-group
    const int comp = lane & 15;         // fragment index dim (A row / B col)

    unsigned int* lTw = &lT[w][0][0];

    // Loop-invariant read pointers (proven r7/r9): element e of the 4-dword
    // group at base X^t4 holds atom X+e; same map for A (lo16) and B (hi16).
    const unsigned t4 = (unsigned)((comp & 7) << 2);
    const unsigned rb = (unsigned)(comp << 6);
    const uint4v* q0p = (const uint4v*)&lTw[rb + (( 8u * g)          ^ t4)];
    const uint4v* q1p = (const uint4v*)&lTw[rb + (( 8u * g + 4)      ^ t4)];
    const uint4v* q2p = (const uint4v*)&lTw[rb + ((32u + 8u * g)     ^ t4)];
    const uint4v* q3p = (const uint4v*)&lTw[rb + ((32u + 8u * g + 4) ^ t4)];

    f32x4 acc = {0.f, 0.f, 0.f, 0.f};

    const int stride = NB * 256;        // 4 waves x 64 atoms per block per iter
    for (int base = (blockIdx.x * 4 + w) * 64; base < N; base += stride) {
        int i = base + lane;
        int ic = i < N ? i : N - 1;
        float x = coo[3 * ic + 0] * 0.5f;   // xyz = coo / UNIT, UNIT = 2
        float y = coo[3 * ic + 1] * 0.5f;
        float z = coo[3 * ic + 2] * 0.5f;
        int num = numbers[ic];

        float r2 = x * x + y * y + z * z;
        float dq = sqrtf(r2);
        float tc = fmaxf(1.f - dq * (1.f / 3.f), 0.f);
        float r = __expf(-0.5f * r2) * (tc * tc);
        if (i >= N) r = 0.f;                 // tail: zero f-row kills the atom

        float fv[4];
        fv[0] = r; fv[1] = r * r2; fv[2] = fv[1] * r2; fv[3] = fv[2] * r2;

        // Solid harmonics (f32), packed (L+1)x(L+1) row-major:
        const float Y00 = 0.28209479177387814f;
        float re11 = -0.34549414947133550f * x;
        float im11 = -0.34549414947133550f * y;
        float re10 =  0.48860251190291992f * z;
        float re22 = -1.11803398874989490f * (x * re11 - y * im11);
        float im22 = -1.11803398874989490f * (x * im11 + y * re11);
        float re21 =  2.23606797749978970f * z * re11;
        float im21 =  2.23606797749978970f * z * im11;
        float re20 =  1.93649167310370850f * (z * re10 - 0.16286750396763996f * r2);
        float re33 = -1.08012344973464350f * (x * re22 - y * im22);
        float im33 = -1.08012344973464350f * (x * im22 + y * re22);
        float re32 =  2.64575131106459070f * z * re22;
        float im32 =  2.64575131106459070f * z * im22;
        float re31 =  2.09165006633518890f * (z * re21 - 0.44721359549995793f * r2 * re11);
        float im31 =  2.09165006633518890f * (z * im21 - 0.44721359549995793f * r2 * im11);
        float re30 =  1.97202659436653870f * (z * re20 - 0.51639777949432220f * r2 * re10);

        float yv[16];
        yv[0] = Y00;  yv[1] = im11; yv[2]  = im22; yv[3]  = im33;
        yv[4] = re11; yv[5] = re10; yv[6]  = im21; yv[7]  = im32;
        yv[8] = re22; yv[9] = re21; yv[10] = re20; yv[11] = im31;
        yv[12] = re33; yv[13] = re32; yv[14] = re31; yv[15] = re30;

        // Packed swizzled stores: dword c = bf16(fsel) | bf16(Y)<<16 in ONE
        // v_cvt_pk_bf16_f32 (S0 -> lo16, S1 -> hi16). All indices but `lane`
        // compile-time.
#pragma unroll
        for (int c = 0; c < 16; ++c) {
            float fsel = (num == (c >> 2)) ? fv[c & 3] : 0.f;
            unsigned d;
            asm("v_cvt_pk_bf16_f32 %0, %1, %2" : "=v"(d) : "v"(fsel), "v"(yv[c]));
            lTw[(c << 6) + (lane ^ ((c & 7) << 2))] = d;
        }

        // Wave-private tile: compiler orders the aliasing writes/reads.
        uint4v q0 = *q0p, q1 = *q1p, q2 = *q2p, q3 = *q3p;

        short8 A0, B0, A1, B1;
#pragma unroll
        for (int e = 0; e < 4; ++e) {
            A0[e]     = (short)(q0[e] & 0xffffu);
            A0[4 + e] = (short)(q1[e] & 0xffffu);
            B0[e]     = (short)(q0[e] >> 16);
            B0[4 + e] = (short)(q1[e] >> 16);
            A1[e]     = (short)(q2[e] & 0xffffu);
            A1[4 + e] = (short)(q3[e] & 0xffffu);
            B1[e]     = (short)(q2[e] >> 16);
            B1[4 + e] = (short)(q3[e] >> 16);
        }

        acc = __builtin_amdgcn_mfma_f32_16x16x32_bf16(A0, B0, acc, 0, 0, 0);
        acc = __builtin_amdgcn_mfma_f32_16x16x32_bf16(A1, B1, acc, 0, 0, 0);
    }

    // C/D layout (m89): lane, reg rr -> c[i=(lane>>4)*4+rr][j=lane&15].
    // Reuse this wave's (idle, wave-private) tile as the reduce buffer.
    float* credw = (float*)&lT[w][0][0];
#pragma unroll
    for (int rr = 0; rr < 4; ++rr)
        credw[((lane >> 4) * 4 + rr) * 16 + (lane & 15)] = acc[rr];
    __syncthreads();

    int tt = threadIdx.x;
    partials[blockIdx.x * 256 + tt] =
        ((float*)&lT[0][0][0])[tt] + ((float*)&lT[1][0][0])[tt] +
        ((float*)&lT[2][0][0])[tt] + ((float*)&lT[3][0][0])[tt];
}

// Fused reduce + finalize, 32 blocks. Each block sums its slice of partials
// into c_ws atomically; last block to finish does the Yr/Yi/nnl contraction.
__global__ void __launch_bounds__(256) soap_reduce_final(
    const float* __restrict__ partials, float* __restrict__ c_ws,
    int* __restrict__ counter, float* __restrict__ out)
{
    __shared__ float cs[256];
    __shared__ int lastflag;
    int t = threadIdx.x;

    float v = 0.f;
    for (int r = blockIdx.x; r < NB; r += 32)
        v += partials[r * 256 + t];           // coalesced, 16 iters
    atomicAdd(&c_ws[t], v);                   // 32 adds/address, device scope
    __syncthreads();
    if (t == 0) {
        __threadfence();                      // release our adds
        lastflag = (atomicAdd(counter, 1) == 31);
    }
    __syncthreads();
    if (!lastflag) return;

    __threadfence();                          // acquire other blocks' adds
    cs[t] = __hip_atomic_load(&c_ws[t], __ATOMIC_RELAXED,
                              __HIP_MEMORY_SCOPE_AGENT);  // L1-bypassing load
    __syncthreads();

    // p1[a,b,n,m,l] = sum_{j<=l} w_j c[b,m,l,j] c[a,n,l,j] (w=1 if j==l else 2)
    // p2[a,b,n,m,l] = sum_{i<l}  2  c[b,m,i,l] c[a,n,i,l]
    // out = (p1+p2) * nnl[n,m,l]
    const float fact[7] = {1.f, 1.f, 2.f, 6.f, 24.f, 120.f, 720.f};
#pragma unroll
    for (int k = 0; k < 4; ++k) {
        int o = k * 256 + t;
        int l = o & 3, m = (o >> 2) & 3, n = (o >> 4) & 3,
            b = (o >> 6) & 3, a = (o >> 8) & 3;
        const float* cbm = &cs[(b * 4 + m) * 16];
        const float* can = &cs[(a * 4 + n) * 16];
        float vv = 0.f;
        for (int j = 0; j <= l; ++j) {
            float wgt = (j == l) ? 1.f : 2.f;
            vv += wgt * cbm[l * 4 + j] * can[l * 4 + j];
        }
        for (int i = 0; i < l; ++i)
            vv += 2.f * cbm[i * 4 + l] * can[i * 4 + l];
        float an = 1.0f / ((float)(2 * l + 1) * (float)(1 << (2 * n + l)) * fact[n] * fact[n + l]);
        float am = 1.0f / ((float)(2 * l + 1) * (float)(1 << (2 * m + l)) * fact[m] * fact[m + l]);
        out[o] = vv * sqrtf(an * am);
    }
}

extern "C" void kernel_launch(void* const* d_in, const int* in_sizes, int n_in,
                              void* d_out, int out_size, void* d_ws, size_t ws_size,
                              hipStream_t stream)
{
    const float* coo = (const float*)d_in[0];
    const int* numbers = (const int*)d_in[1];
    int N = in_sizes[1];                 // 1,000,000 atoms

    float* c_ws = (float*)d_ws;          // [256] accumulated c
    int* counter = (int*)((float*)d_ws + 256);  // ticket counter
    float* partials = (float*)d_ws + 512;       // [NB*256] stage-1 partials
    // ws requirement: (512 + 131072) * 4 B ~= 0.53 MB.

    hipLaunchKernelGGL(soap_accum, dim3(NB), dim3(256), 0, stream,
                       coo, numbers, N, partials, c_ws, counter);
    hipLaunchKernelGGL(soap_reduce_final, dim3(32), dim3(256), 0, stream,
                       partials, c_ws, counter, (float*)d_out);
}